// Round 1
// baseline (23726.141 us; speedup 1.0000x reference)
//
#include <hip/hip_runtime.h>
#include <math.h>

// ---------------------------------------------------------------------------
// ViT forward (B=32, N=197, D=768, FF=3072, 12 layers) — round 0: f32 baseline
// Priority: bit-faithful gumbel noise (JAX threefry, partitionable variant)
// and correct end-to-end structure. GEMMs: 64x64x16 tiled f32 (to be replaced
// by bf16 MFMA in later rounds).
// ---------------------------------------------------------------------------

namespace {
constexpr int DIM    = 768;
constexpr int FF_DIM = 3072;
constexpr int NTOK   = 197;
constexpr int NBATCH = 32;
constexpr int NLAYER = 12;
constexpr int ROWS   = NBATCH * NTOK;      // 6304
constexpr int NPATCH = 196;
constexpr int PROWS  = NBATCH * NPATCH;    // 6272
constexpr float LN_EPS = 1e-5f;
}

// ---------------- threefry2x32 gumbel (JAX jax.random.key(1)) ---------------
__device__ __forceinline__ unsigned rotl32(unsigned v, int d) {
  return (v << d) | (v >> (32 - d));
}

__device__ __forceinline__ float gumbel_noise(unsigned idx) {
  // key(1) -> (k1,k2) = (0,1); partitionable path: counts = (0, idx),
  // bits = out0 ^ out1.
  const unsigned ks0 = 0u, ks1 = 1u, ks2 = 0x1BD11BDBu; // 0^1^0x1BD11BDA
  unsigned x0 = 0u + ks0;
  unsigned x1 = idx + ks1;
#define TFR(r) { x0 += x1; x1 = rotl32(x1, (r)); x1 ^= x0; }
  TFR(13) TFR(15) TFR(26) TFR(6)   x0 += ks1; x1 += ks2 + 1u;
  TFR(17) TFR(29) TFR(16) TFR(24)  x0 += ks2; x1 += ks0 + 2u;
  TFR(13) TFR(15) TFR(26) TFR(6)   x0 += ks0; x1 += ks1 + 3u;
  TFR(17) TFR(29) TFR(16) TFR(24)  x0 += ks1; x1 += ks2 + 4u;
  TFR(13) TFR(15) TFR(26) TFR(6)   x0 += ks2; x1 += ks0 + 5u;
#undef TFR
  unsigned bits = x0 ^ x1;
  // uniform in [tiny, 1): f = bitcast(bits>>9 | 1.0f-bits) - 1; u = max(tiny, f*(1-tiny)+tiny)
  float f = __uint_as_float((bits >> 9) | 0x3f800000u) - 1.0f;
  const float tiny = 1.17549435e-38f;
  float u = fmaxf(tiny, f + tiny);   // (1-tiny) rounds to 1.0f in f32
  return -logf(-logf(u));
}

// ---------------- block reduction helpers ----------------------------------
__device__ __forceinline__ float block_reduce_sum(float val, float* red) {
  int tid = threadIdx.x;
  red[tid] = val; __syncthreads();
  for (int off = 128; off > 0; off >>= 1) {
    if (tid < off) red[tid] += red[tid + off];
    __syncthreads();
  }
  float r = red[0];
  __syncthreads();
  return r;
}

__device__ __forceinline__ float block_reduce_max(float val, float* red) {
  int tid = threadIdx.x;
  red[tid] = val; __syncthreads();
  for (int off = 128; off > 0; off >>= 1) {
    if (tid < off) red[tid] = fmaxf(red[tid], red[tid + off]);
    __syncthreads();
  }
  float r = red[0];
  __syncthreads();
  return r;
}

// ---------------- generic tiled f32 GEMM ------------------------------------
// C[bz] = A[bz] @ (B[bz] or B[bz]^T) + bias (+ exact GELU)
// BM=BN=64, BK=16, 256 threads, 4x4 per thread.
template<bool TRB, bool ACT_GELU>
__global__ void gemm_kernel(const float* __restrict__ A, long sA, int lda,
                            const float* __restrict__ B, long sB, int ldb,
                            float* __restrict__ C, long sC, int ldc,
                            int M, int N, int K,
                            const float* __restrict__ bias) {
  __shared__ float As[16][64];
  __shared__ float Bs[16][64];
  const int bz = blockIdx.z;
  A += (long)bz * sA; B += (long)bz * sB; C += (long)bz * sC;
  const int tid = threadIdx.x;
  const int tx = tid & 15, ty = tid >> 4;
  const int row0 = blockIdx.x * 64, col0 = blockIdx.y * 64;

  float acc[4][4] = {{0.f,0.f,0.f,0.f},{0.f,0.f,0.f,0.f},
                     {0.f,0.f,0.f,0.f},{0.f,0.f,0.f,0.f}};

  for (int k0 = 0; k0 < K; k0 += 16) {
    { // A tile -> As[k][m]
      const int m  = tid >> 2;
      const int k4 = (tid & 3) << 2;
      const int gm = row0 + m;
      #pragma unroll
      for (int j = 0; j < 4; j++) {
        const int gk = k0 + k4 + j;
        float v = 0.f;
        if (gm < M && gk < K) v = A[(long)gm * lda + gk];
        As[k4 + j][m] = v;
      }
    }
    if (TRB) { // B^T tile: Bs[k][n] = B[n][k]
      const int n  = tid >> 2;
      const int k4 = (tid & 3) << 2;
      const int gn = col0 + n;
      #pragma unroll
      for (int j = 0; j < 4; j++) {
        const int gk = k0 + k4 + j;
        float v = 0.f;
        if (gn < N && gk < K) v = B[(long)gn * ldb + gk];
        Bs[k4 + j][n] = v;
      }
    } else {   // Bs[k][n] = B[k][n]
      const int kk = tid >> 6;   // 0..3
      const int n  = tid & 63;
      const int gn = col0 + n;
      #pragma unroll
      for (int j = 0; j < 4; j++) {
        const int gk = k0 + kk + (j << 2);
        float v = 0.f;
        if (gk < K && gn < N) v = B[(long)gk * ldb + gn];
        Bs[kk + (j << 2)][n] = v;
      }
    }
    __syncthreads();
    #pragma unroll
    for (int kk = 0; kk < 16; kk++) {
      float a[4], b[4];
      #pragma unroll
      for (int i = 0; i < 4; i++) a[i] = As[kk][(ty << 2) + i];
      #pragma unroll
      for (int j = 0; j < 4; j++) b[j] = Bs[kk][(tx << 2) + j];
      #pragma unroll
      for (int i = 0; i < 4; i++)
        #pragma unroll
        for (int j = 0; j < 4; j++)
          acc[i][j] += a[i] * b[j];
    }
    __syncthreads();
  }

  #pragma unroll
  for (int i = 0; i < 4; i++) {
    const int r = row0 + (ty << 2) + i;
    if (r >= M) continue;
    #pragma unroll
    for (int j = 0; j < 4; j++) {
      const int c = col0 + (tx << 2) + j;
      if (c >= N) continue;
      float v = acc[i][j];
      if (bias) v += bias[c];
      if (ACT_GELU) v = 0.5f * v * (1.0f + erff(v * 0.70710678118654752f));
      C[(long)r * ldc + c] = v;
    }
  }
}

// ---------------- patch embedding helpers -----------------------------------
__global__ void im2col_kernel(const float* __restrict__ x, float* __restrict__ col) {
  const int p = blockIdx.x;              // 0..6271 = b*196 + pidx
  const int b = p / NPATCH, pi = p % NPATCH;
  const int h = pi / 14, w = pi % 14;
  for (int e = threadIdx.x; e < DIM; e += 256) {
    const int c = e >> 8, r = e & 255, pp = r >> 4, q = r & 15;
    col[(long)p * DIM + e] =
        x[(((long)b * 3 + c) * 224 + h * 16 + pp) * 224 + w * 16 + q];
  }
}

__global__ void assemble_kernel(const float* __restrict__ tmp,
                                const float* __restrict__ cls,
                                const float* __restrict__ pos,
                                float* __restrict__ tok) {
  const int row = blockIdx.x;            // 0..6303
  const int b = row / NTOK, n = row % NTOK;
  for (int d = threadIdx.x; d < DIM; d += 256) {
    float v = (n == 0) ? cls[d] : tmp[(long)(b * NPATCH + n - 1) * DIM + d];
    tok[(long)row * DIM + d] = v + pos[n * DIM + d];
  }
}

// ---------------- fused gumbel + softmax (row of 197) -----------------------
__global__ void softmax_kernel(float* __restrict__ sc, int layer) {
  __shared__ float red[256];
  const int row = blockIdx.x;            // b*197 + n
  const int b = row / NTOK, n = row % NTOK;
  const int tid = threadIdx.x;
  const long base = (long)row * NTOK;
  const float inv_sqrt_d = 0.036084391824351615f;  // 1/sqrt(768)

  float x = -INFINITY;
  if (tid < NTOK) {
    const unsigned idx =
        ((((unsigned)layer * NBATCH + b) * NTOK + n) * NTOK) + tid;
    x = sc[base + tid] * inv_sqrt_d + gumbel_noise(idx);
  }
  const float mx = block_reduce_max(x, red);
  float ex = (tid < NTOK) ? expf(x - mx) : 0.f;
  const float s = block_reduce_sum(ex, red);
  if (tid < NTOK) sc[base + tid] = ex / s;
}

// ---------------- residual add + LayerNorm (in-place on tok) ---------------
__global__ void add_ln_kernel(float* __restrict__ tok,
                              const float* __restrict__ res,
                              const float* __restrict__ g,
                              const float* __restrict__ beta) {
  __shared__ float red[256];
  const int row = blockIdx.x;
  const int tid = threadIdx.x;
  const long base = (long)row * DIM;
  float v[3];
  float s = 0.f;
  #pragma unroll
  for (int i = 0; i < 3; i++) {
    const int d = tid + (i << 8);
    v[i] = tok[base + d] + res[base + d];
    s += v[i];
  }
  const float mean = block_reduce_sum(s, red) * (1.0f / DIM);
  float s2 = 0.f;
  #pragma unroll
  for (int i = 0; i < 3; i++) { const float dd = v[i] - mean; s2 += dd * dd; }
  const float var = block_reduce_sum(s2, red) * (1.0f / DIM);
  const float inv = 1.0f / sqrtf(var + LN_EPS);
  #pragma unroll
  for (int i = 0; i < 3; i++) {
    const int d = tid + (i << 8);
    tok[base + d] = (v[i] - mean) * inv * g[d] + beta[d];
  }
}

// ---------------- final LN (cls row) + head ---------------------------------
__global__ void head_kernel(const float* __restrict__ tok,
                            const float* __restrict__ g,
                            const float* __restrict__ beta,
                            const float* __restrict__ hw,
                            const float* __restrict__ hb,
                            float* __restrict__ out) {
  __shared__ float red[256];
  __shared__ float xn[DIM];
  const int b = blockIdx.x;
  const int tid = threadIdx.x;
  const float* xr = tok + (long)b * NTOK * DIM;   // cls row (n=0)
  float v[3];
  float s = 0.f;
  #pragma unroll
  for (int i = 0; i < 3; i++) { v[i] = xr[tid + (i << 8)]; s += v[i]; }
  const float mean = block_reduce_sum(s, red) * (1.0f / DIM);
  float s2 = 0.f;
  #pragma unroll
  for (int i = 0; i < 3; i++) { const float dd = v[i] - mean; s2 += dd * dd; }
  const float var = block_reduce_sum(s2, red) * (1.0f / DIM);
  const float inv = 1.0f / sqrtf(var + LN_EPS);
  #pragma unroll
  for (int i = 0; i < 3; i++) {
    const int d = tid + (i << 8);
    xn[d] = (v[i] - mean) * inv * g[d] + beta[d];
  }
  __syncthreads();
  for (int c = tid; c < 100; c += 256) {
    float acc = hb[c];
    for (int d = 0; d < DIM; d++) acc += xn[d] * hw[d * 100 + c];
    out[b * 100 + c] = acc;
  }
}

// ---------------------------------------------------------------------------
extern "C" void kernel_launch(void* const* d_in, const int* in_sizes, int n_in,
                              void* d_out, int out_size, void* d_ws, size_t ws_size,
                              hipStream_t stream) {
  const float* x        = (const float*)d_in[0];
  const float* patch_w  = (const float*)d_in[1];
  const float* patch_b  = (const float*)d_in[2];
  const float* cls_tok  = (const float*)d_in[3];
  const float* pos_emb  = (const float*)d_in[4];
  const float* Wq       = (const float*)d_in[5];
  const float* bq       = (const float*)d_in[6];
  const float* Wk       = (const float*)d_in[7];
  const float* bk       = (const float*)d_in[8];
  const float* Wv       = (const float*)d_in[9];
  const float* bv       = (const float*)d_in[10];
  const float* W1       = (const float*)d_in[11];
  const float* b1       = (const float*)d_in[12];
  const float* W2       = (const float*)d_in[13];
  const float* b2       = (const float*)d_in[14];
  const float* ln1_g    = (const float*)d_in[15];
  const float* ln1_b    = (const float*)d_in[16];
  const float* ln2_g    = (const float*)d_in[17];
  const float* ln2_b    = (const float*)d_in[18];
  const float* lnf_g    = (const float*)d_in[19];
  const float* lnf_b    = (const float*)d_in[20];
  const float* head_w   = (const float*)d_in[21];
  const float* head_b   = (const float*)d_in[22];
  float* out = (float*)d_out;

  // workspace layout (floats)
  const long TOKSZ = (long)ROWS * DIM;        // 4,841,472
  float* ws  = (float*)d_ws;
  float* tok = ws;
  float* qb  = tok + TOKSZ;
  float* kb  = qb  + TOKSZ;
  float* vb  = kb  + TOKSZ;
  float* b4  = vb  + TOKSZ;                   // attn-out / ff2-out / im2col
  float* big = b4  + TOKSZ;                   // ff1 (6304x3072) / scores / patch tmp

  // ---- patch embedding: im2col -> GEMM -> assemble with cls+pos ----
  im2col_kernel<<<PROWS, 256, 0, stream>>>(x, b4);
  {
    dim3 g(PROWS / 64, DIM / 64, 1);          // 98 x 12
    gemm_kernel<false, false><<<g, 256, 0, stream>>>(
        b4, 0, DIM, patch_w, 0, DIM, big, 0, DIM, PROWS, DIM, DIM, patch_b);
  }
  assemble_kernel<<<ROWS, 256, 0, stream>>>(big, cls_tok, pos_emb, tok);

  const long DD = (long)DIM * DIM;
  const long TOKSTRIDE = (long)NTOK * DIM;    // 151,296
  const long SCSTRIDE  = (long)NTOK * NTOK;   // 38,809

  for (int l = 0; l < NLAYER; l++) {
    dim3 gqkv((ROWS + 63) / 64, DIM / 64, 1); // 99 x 12
    gemm_kernel<false, false><<<gqkv, 256, 0, stream>>>(
        tok, 0, DIM, Wq + (long)l * DD, 0, DIM, qb, 0, DIM,
        ROWS, DIM, DIM, bq + l * DIM);
    gemm_kernel<false, false><<<gqkv, 256, 0, stream>>>(
        tok, 0, DIM, Wk + (long)l * DD, 0, DIM, kb, 0, DIM,
        ROWS, DIM, DIM, bk + l * DIM);
    gemm_kernel<false, false><<<gqkv, 256, 0, stream>>>(
        tok, 0, DIM, Wv + (long)l * DD, 0, DIM, vb, 0, DIM,
        ROWS, DIM, DIM, bv + l * DIM);

    dim3 gs((NTOK + 63) / 64, (NTOK + 63) / 64, NBATCH); // 4 x 4 x 32
    gemm_kernel<true, false><<<gs, 256, 0, stream>>>(
        qb, TOKSTRIDE, DIM, kb, TOKSTRIDE, DIM, big, SCSTRIDE, NTOK,
        NTOK, NTOK, DIM, nullptr);

    softmax_kernel<<<ROWS, 256, 0, stream>>>(big, l);

    dim3 gp((NTOK + 63) / 64, DIM / 64, NBATCH);         // 4 x 12 x 32
    gemm_kernel<false, false><<<gp, 256, 0, stream>>>(
        big, SCSTRIDE, NTOK, vb, TOKSTRIDE, DIM, b4, TOKSTRIDE, DIM,
        NTOK, DIM, NTOK, nullptr);

    add_ln_kernel<<<ROWS, 256, 0, stream>>>(tok, b4, ln1_g + l * DIM, ln1_b + l * DIM);

    dim3 gf1((ROWS + 63) / 64, FF_DIM / 64, 1);          // 99 x 48
    gemm_kernel<false, true><<<gf1, 256, 0, stream>>>(
        tok, 0, DIM, W1 + (long)l * DIM * FF_DIM, 0, FF_DIM, big, 0, FF_DIM,
        ROWS, FF_DIM, DIM, b1 + l * FF_DIM);

    dim3 gf2((ROWS + 63) / 64, DIM / 64, 1);             // 99 x 12
    gemm_kernel<false, false><<<gf2, 256, 0, stream>>>(
        big, 0, FF_DIM, W2 + (long)l * FF_DIM * DIM, 0, DIM, b4, 0, DIM,
        ROWS, DIM, FF_DIM, b2 + l * DIM);

    add_ln_kernel<<<ROWS, 256, 0, stream>>>(tok, b4, ln2_g + l * DIM, ln2_b + l * DIM);
  }

  head_kernel<<<NBATCH, 256, 0, stream>>>(tok, lnf_g, lnf_b, head_w, head_b, out);
}

// Round 2
// 4066.565 us; speedup vs baseline: 5.8344x; 5.8344x over previous
//
#include <hip/hip_runtime.h>
#include <hip/hip_bf16.h>
#include <math.h>

// ---------------------------------------------------------------------------
// ViT forward (B=32, N=197, D=768, FF=3072, 12 layers) — round 1:
// all GEMMs -> bf16 MFMA (16x16x32), m97 structure (128x128 tile, BK=64,
// global_load_lds width-16, linear LDS). f32 residual/LN/softmax.
// ---------------------------------------------------------------------------

namespace {
constexpr int DIM    = 768;
constexpr int FF_DIM = 3072;
constexpr int NTOK   = 197;
constexpr int NBATCH = 32;
constexpr int NLAYER = 12;
constexpr int ROWS   = NBATCH * NTOK;      // 6304
constexpr int NPATCH = 196;
constexpr int PROWS  = NBATCH * NPATCH;    // 6272
constexpr int KVPAD  = 256;                // padded K for P@V GEMM
constexpr float LN_EPS = 1e-5f;
}

typedef __attribute__((ext_vector_type(8))) __bf16 bf16x8;
typedef __attribute__((ext_vector_type(4))) float  f32x4;

// ---------------- threefry2x32 gumbel (JAX jax.random.key(1)) ---------------
__device__ __forceinline__ unsigned rotl32(unsigned v, int d) {
  return (v << d) | (v >> (32 - d));
}

__device__ __forceinline__ float gumbel_noise(unsigned idx) {
  const unsigned ks0 = 0u, ks1 = 1u, ks2 = 0x1BD11BDBu;
  unsigned x0 = 0u + ks0;
  unsigned x1 = idx + ks1;
#define TFR(r) { x0 += x1; x1 = rotl32(x1, (r)); x1 ^= x0; }
  TFR(13) TFR(15) TFR(26) TFR(6)   x0 += ks1; x1 += ks2 + 1u;
  TFR(17) TFR(29) TFR(16) TFR(24)  x0 += ks2; x1 += ks0 + 2u;
  TFR(13) TFR(15) TFR(26) TFR(6)   x0 += ks0; x1 += ks1 + 3u;
  TFR(17) TFR(29) TFR(16) TFR(24)  x0 += ks1; x1 += ks2 + 4u;
  TFR(13) TFR(15) TFR(26) TFR(6)   x0 += ks2; x1 += ks0 + 5u;
#undef TFR
  unsigned bits = x0 ^ x1;
  float f = __uint_as_float((bits >> 9) | 0x3f800000u) - 1.0f;
  const float tiny = 1.17549435e-38f;
  float u = fmaxf(tiny, f + tiny);
  return -logf(-logf(u));
}

// ---------------- block reduction helpers ----------------------------------
__device__ __forceinline__ float block_reduce_sum(float val, float* red) {
  int tid = threadIdx.x;
  red[tid] = val; __syncthreads();
  for (int off = 128; off > 0; off >>= 1) {
    if (tid < off) red[tid] += red[tid + off];
    __syncthreads();
  }
  float r = red[0];
  __syncthreads();
  return r;
}

__device__ __forceinline__ float block_reduce_max(float val, float* red) {
  int tid = threadIdx.x;
  red[tid] = val; __syncthreads();
  for (int off = 128; off > 0; off >>= 1) {
    if (tid < off) red[tid] = fmaxf(red[tid], red[tid + off]);
    __syncthreads();
  }
  float r = red[0];
  __syncthreads();
  return r;
}

// ---------------- async 16B global -> LDS ----------------------------------
__device__ __forceinline__ void async_copy16(const void* g, void* l) {
  __builtin_amdgcn_global_load_lds(
      (const __attribute__((address_space(1))) unsigned*)g,
      (__attribute__((address_space(3))) unsigned*)l, 16, 0, 0);
}

// ---------------- bf16 MFMA GEMM (NT): C = A * B^T --------------------------
// A: [M][K] bf16 row-major (lda, batch stride sA)
// B: [N][K] bf16 row-major (ldb, batch stride sB)   <- "B^T" operand
// C: f32 (STORE=0), bf16 (STORE=1), bf16 transposed C^T (STORE=2)
// 128x128 tile, BK=64, 256 threads (4 waves as 2x2 of 64x64).
template<int STORE, bool GELU>
__global__ void mm_nt(const __hip_bfloat16* __restrict__ A, long sA, int lda,
                      const __hip_bfloat16* __restrict__ B, long sB, int ldb,
                      void* __restrict__ Cv, long sC, int ldc,
                      int M, int N, int K, const float* __restrict__ bias) {
  __shared__ __hip_bfloat16 As[128 * 64];
  __shared__ __hip_bfloat16 Bs[128 * 64];
  const int bz = blockIdx.z;
  A += (long)bz * sA;
  B += (long)bz * sB;
  const int row0 = blockIdx.x * 128, col0 = blockIdx.y * 128;
  const int tid = threadIdx.x, lane = tid & 63, wid = tid >> 6;
  const int wr = (wid >> 1) * 64, wc = (wid & 1) * 64;
  const int fr = lane & 15;      // fragment row (A) / col (B) index
  const int kh = lane >> 4;      // k-chunk 0..3 (k offset kh*8)
  f32x4 acc[4][4] = {};

  const int elem = wid * 512 + lane * 8;  // within a 4KB chunk (2048 elems)

  for (int k0 = 0; k0 < K; k0 += 64) {
    #pragma unroll
    for (int c = 0; c < 4; c++) {
      const int e = c * 2048 + elem;
      const int r = e >> 6, kk = e & 63;
      async_copy16(A + (long)(row0 + r) * lda + k0 + kk,
                   (char*)As + c * 4096 + wid * 1024);
    }
    #pragma unroll
    for (int c = 0; c < 4; c++) {
      const int e = c * 2048 + elem;
      const int r = e >> 6, kk = e & 63;
      async_copy16(B + (long)(col0 + r) * ldb + k0 + kk,
                   (char*)Bs + c * 4096 + wid * 1024);
    }
    __syncthreads();
    #pragma unroll
    for (int ks = 0; ks < 2; ks++) {
      bf16x8 a[4], b[4];
      #pragma unroll
      for (int i = 0; i < 4; i++)
        a[i] = *(const bf16x8*)&As[(wr + i * 16 + fr) * 64 + ks * 32 + kh * 8];
      #pragma unroll
      for (int j = 0; j < 4; j++)
        b[j] = *(const bf16x8*)&Bs[(wc + j * 16 + fr) * 64 + ks * 32 + kh * 8];
      #pragma unroll
      for (int i = 0; i < 4; i++)
        #pragma unroll
        for (int j = 0; j < 4; j++)
          acc[i][j] = __builtin_amdgcn_mfma_f32_16x16x32_bf16(
              a[i], b[j], acc[i][j], 0, 0, 0);
    }
    __syncthreads();
  }

  // epilogue: D layout col = lane&15, row = (lane>>4)*4 + reg
  #pragma unroll
  for (int i = 0; i < 4; i++) {
    #pragma unroll
    for (int j = 0; j < 4; j++) {
      #pragma unroll
      for (int t = 0; t < 4; t++) {
        const int r  = row0 + wr + i * 16 + kh * 4 + t;
        const int cc = col0 + wc + j * 16 + fr;
        if (r < M && cc < N) {
          float v = acc[i][j][t];
          if (bias) v += bias[cc];
          if (GELU) v = 0.5f * v * (1.0f + erff(v * 0.70710678118654752f));
          if (STORE == 0)
            ((float*)Cv)[(long)bz * sC + (long)r * ldc + cc] = v;
          else if (STORE == 1)
            ((__hip_bfloat16*)Cv)[(long)bz * sC + (long)r * ldc + cc] =
                __float2bfloat16(v);
          else
            ((__hip_bfloat16*)Cv)[(long)bz * sC + (long)cc * ldc + r] =
                __float2bfloat16(v);
        }
      }
    }
  }
}

// ---------------- f32 [K][N] -> bf16 [N][K] transpose ------------------------
__global__ void transpose_bf16_kernel(const float* __restrict__ W,
                                      __hip_bfloat16* __restrict__ Wt,
                                      int K, int N) {
  __shared__ float t[32][33];
  const int k0 = blockIdx.x * 32, n0 = blockIdx.y * 32;
  const int tx = threadIdx.x & 31, ty = threadIdx.x >> 5;  // 32x8
  #pragma unroll
  for (int i = 0; i < 32; i += 8)
    t[ty + i][tx] = W[(long)(k0 + ty + i) * N + n0 + tx];
  __syncthreads();
  #pragma unroll
  for (int i = 0; i < 32; i += 8)
    Wt[(long)(n0 + ty + i) * K + k0 + tx] = __float2bfloat16(t[tx][ty + i]);
}

// ---------------- zero-fill (float4 granular) -------------------------------
__global__ void zero_kernel(float* __restrict__ p, long n4) {
  const long i0 = (long)blockIdx.x * blockDim.x + threadIdx.x;
  f32x4 z = {0.f, 0.f, 0.f, 0.f};
  for (long i = i0; i < n4; i += (long)gridDim.x * blockDim.x)
    ((f32x4*)p)[i] = z;
}

// ---------------- patch embedding helpers -----------------------------------
__global__ void im2col_kernel(const float* __restrict__ x,
                              __hip_bfloat16* __restrict__ col) {
  const int p = blockIdx.x;              // b*196 + pidx
  const int b = p / NPATCH, pi = p % NPATCH;
  const int h = pi / 14, w = pi % 14;
  for (int e = threadIdx.x; e < DIM; e += 256) {
    const int c = e >> 8, r = e & 255, pp = r >> 4, q = r & 15;
    col[(long)p * DIM + e] = __float2bfloat16(
        x[(((long)b * 3 + c) * 224 + h * 16 + pp) * 224 + w * 16 + q]);
  }
}

__global__ void assemble_kernel(const float* __restrict__ tmp,
                                const float* __restrict__ cls,
                                const float* __restrict__ pos,
                                float* __restrict__ tok,
                                __hip_bfloat16* __restrict__ tok_bf) {
  const int row = blockIdx.x;            // 0..6303
  const int b = row / NTOK, n = row % NTOK;
  for (int d = threadIdx.x; d < DIM; d += 256) {
    float v = (n == 0) ? cls[d] : tmp[(long)(b * NPATCH + n - 1) * DIM + d];
    v += pos[n * DIM + d];
    tok[(long)row * DIM + d] = v;
    tok_bf[(long)row * DIM + d] = __float2bfloat16(v);
  }
}

// ---------------- fused gumbel + softmax ------------------------------------
// reads f32 scores [197] (packed ldc=197), writes bf16 P row of KVPAD=256
// (cols 197..255 zeroed -> K padding for P@V).
__global__ void softmax_kernel(const float* __restrict__ sc,
                               __hip_bfloat16* __restrict__ P, int layer) {
  __shared__ float red[256];
  const int row = blockIdx.x;            // b*197 + n
  const int b = row / NTOK, n = row % NTOK;
  const int tid = threadIdx.x;
  const long base = (long)row * NTOK;
  const float inv_sqrt_d = 0.036084391824351615f;  // 1/sqrt(768)

  float x = -INFINITY;
  if (tid < NTOK) {
    const unsigned idx =
        ((((unsigned)layer * NBATCH + b) * NTOK + n) * NTOK) + tid;
    x = sc[base + tid] * inv_sqrt_d + gumbel_noise(idx);
  }
  const float mx = block_reduce_max(x, red);
  float ex = (tid < NTOK) ? expf(x - mx) : 0.f;
  const float s = block_reduce_sum(ex, red);
  const float pv = (tid < NTOK) ? ex / s : 0.f;
  P[(long)row * KVPAD + tid] = __float2bfloat16(pv);
}

// ---------------- residual add + LayerNorm (f32 + bf16 dual store) ----------
__global__ void add_ln_kernel(float* __restrict__ tok,
                              __hip_bfloat16* __restrict__ tok_bf,
                              const float* __restrict__ res,
                              const float* __restrict__ g,
                              const float* __restrict__ beta) {
  __shared__ float red[256];
  const int row = blockIdx.x;
  const int tid = threadIdx.x;
  const long base = (long)row * DIM;
  float v[3];
  float s = 0.f;
  #pragma unroll
  for (int i = 0; i < 3; i++) {
    const int d = tid + (i << 8);
    v[i] = tok[base + d] + res[base + d];
    s += v[i];
  }
  const float mean = block_reduce_sum(s, red) * (1.0f / DIM);
  float s2 = 0.f;
  #pragma unroll
  for (int i = 0; i < 3; i++) { const float dd = v[i] - mean; s2 += dd * dd; }
  const float var = block_reduce_sum(s2, red) * (1.0f / DIM);
  const float inv = 1.0f / sqrtf(var + LN_EPS);
  #pragma unroll
  for (int i = 0; i < 3; i++) {
    const int d = tid + (i << 8);
    const float o = (v[i] - mean) * inv * g[d] + beta[d];
    tok[base + d] = o;
    tok_bf[base + d] = __float2bfloat16(o);
  }
}

// ---------------- final LN (cls row) + head ---------------------------------
__global__ void head_kernel(const float* __restrict__ tok,
                            const float* __restrict__ g,
                            const float* __restrict__ beta,
                            const float* __restrict__ hw,
                            const float* __restrict__ hb,
                            float* __restrict__ out) {
  __shared__ float red[256];
  __shared__ float xn[DIM];
  const int b = blockIdx.x;
  const int tid = threadIdx.x;
  const float* xr = tok + (long)b * NTOK * DIM;   // cls row (n=0)
  float v[3];
  float s = 0.f;
  #pragma unroll
  for (int i = 0; i < 3; i++) { v[i] = xr[tid + (i << 8)]; s += v[i]; }
  const float mean = block_reduce_sum(s, red) * (1.0f / DIM);
  float s2 = 0.f;
  #pragma unroll
  for (int i = 0; i < 3; i++) { const float dd = v[i] - mean; s2 += dd * dd; }
  const float var = block_reduce_sum(s2, red) * (1.0f / DIM);
  const float inv = 1.0f / sqrtf(var + LN_EPS);
  #pragma unroll
  for (int i = 0; i < 3; i++) {
    const int d = tid + (i << 8);
    xn[d] = (v[i] - mean) * inv * g[d] + beta[d];
  }
  __syncthreads();
  for (int c = tid; c < 100; c += 256) {
    float acc = hb[c];
    for (int d = 0; d < DIM; d++) acc += xn[d] * hw[d * 100 + c];
    out[b * 100 + c] = acc;
  }
}

// ---------------------------------------------------------------------------
extern "C" void kernel_launch(void* const* d_in, const int* in_sizes, int n_in,
                              void* d_out, int out_size, void* d_ws, size_t ws_size,
                              hipStream_t stream) {
  const float* x        = (const float*)d_in[0];
  const float* patch_w  = (const float*)d_in[1];
  const float* patch_b  = (const float*)d_in[2];
  const float* cls_tok  = (const float*)d_in[3];
  const float* pos_emb  = (const float*)d_in[4];
  const float* Wq       = (const float*)d_in[5];
  const float* bq       = (const float*)d_in[6];
  const float* Wk       = (const float*)d_in[7];
  const float* bk       = (const float*)d_in[8];
  const float* Wv       = (const float*)d_in[9];
  const float* bv       = (const float*)d_in[10];
  const float* W1       = (const float*)d_in[11];
  const float* b1       = (const float*)d_in[12];
  const float* W2       = (const float*)d_in[13];
  const float* b2       = (const float*)d_in[14];
  const float* ln1_g    = (const float*)d_in[15];
  const float* ln1_b    = (const float*)d_in[16];
  const float* ln2_g    = (const float*)d_in[17];
  const float* ln2_b    = (const float*)d_in[18];
  const float* lnf_g    = (const float*)d_in[19];
  const float* lnf_b    = (const float*)d_in[20];
  const float* head_w   = (const float*)d_in[21];
  const float* head_b   = (const float*)d_in[22];
  float* out = (float*)d_out;

  // ---- workspace layout ----
  float* fb = (float*)d_ws;
  long fo = 0;
  float* tok    = fb + fo; fo += 6400L * DIM;        // f32 residual stream
  float* b4     = fb + fo; fo += 6400L * DIM;        // attn/ff2/patch out f32
  float* scbuf  = fb + fo; fo += 1241920L;           // scores f32 (32*197*197)
  __hip_bfloat16* hbuf = (__hip_bfloat16*)(fb + fo);
  long ho = 0;
  __hip_bfloat16* tok_bf = hbuf + ho; ho += 6400L * DIM;
  __hip_bfloat16* qb     = hbuf + ho; ho += 6368L * DIM;
  __hip_bfloat16* kb     = hbuf + ho; ho += 6368L * DIM;
  __hip_bfloat16* vt     = hbuf + ho; ho += (long)NBATCH * DIM * KVPAD;
  __hip_bfloat16* Pb     = hbuf + ho; ho += 6368L * KVPAD;
  __hip_bfloat16* ffout  = hbuf + ho; ho += 6400L * FF_DIM;
  __hip_bfloat16* wq_t   = hbuf + ho; ho += (long)DIM * DIM;
  __hip_bfloat16* wk_t   = hbuf + ho; ho += (long)DIM * DIM;
  __hip_bfloat16* wv_t   = hbuf + ho; ho += (long)DIM * DIM;
  __hip_bfloat16* w1_t   = hbuf + ho; ho += (long)FF_DIM * DIM;
  __hip_bfloat16* w2_t   = hbuf + ho; ho += (long)DIM * FF_DIM;

  const long DD = (long)DIM * DIM;
  const long TOKSTRIDE = (long)NTOK * DIM;     // 151,296
  const long SCSTRIDE  = (long)NTOK * NTOK;    // 38,809
  const long VTSTRIDE  = (long)DIM * KVPAD;    // 196,608
  const long PSTRIDE   = (long)NTOK * KVPAD;   // 50,432

  // zero vt once per call (K-pad cols 197..255 stay zero all layers)
  zero_kernel<<<512, 256, 0, stream>>>((float*)vt,
      ((long)NBATCH * DIM * KVPAD) / 8);

  // ---- patch embedding ----
  im2col_kernel<<<PROWS, 256, 0, stream>>>(x, qb);  // reuse qb as im2col buf
  transpose_bf16_kernel<<<dim3(DIM / 32, DIM / 32), 256, 0, stream>>>(
      patch_w, wq_t, DIM, DIM);
  mm_nt<0, false><<<dim3(PROWS / 128, DIM / 128), 256, 0, stream>>>(
      qb, 0, DIM, wq_t, 0, DIM, b4, 0, DIM, PROWS, DIM, DIM, patch_b);
  assemble_kernel<<<ROWS, 256, 0, stream>>>(b4, cls_tok, pos_emb, tok, tok_bf);

  for (int l = 0; l < NLAYER; l++) {
    transpose_bf16_kernel<<<dim3(DIM / 32, DIM / 32), 256, 0, stream>>>(
        Wq + l * DD, wq_t, DIM, DIM);
    transpose_bf16_kernel<<<dim3(DIM / 32, DIM / 32), 256, 0, stream>>>(
        Wk + l * DD, wk_t, DIM, DIM);
    transpose_bf16_kernel<<<dim3(DIM / 32, DIM / 32), 256, 0, stream>>>(
        Wv + l * DD, wv_t, DIM, DIM);
    transpose_bf16_kernel<<<dim3(DIM / 32, FF_DIM / 32), 256, 0, stream>>>(
        W1 + (long)l * DIM * FF_DIM, w1_t, DIM, FF_DIM);
    transpose_bf16_kernel<<<dim3(FF_DIM / 32, DIM / 32), 256, 0, stream>>>(
        W2 + (long)l * FF_DIM * DIM, w2_t, FF_DIM, DIM);

    // Q, K (flat M=6304, bf16 out)
    mm_nt<1, false><<<dim3(50, DIM / 128), 256, 0, stream>>>(
        tok_bf, 0, DIM, wq_t, 0, DIM, qb, 0, DIM, ROWS, DIM, DIM, bq + l * DIM);
    mm_nt<1, false><<<dim3(50, DIM / 128), 256, 0, stream>>>(
        tok_bf, 0, DIM, wk_t, 0, DIM, kb, 0, DIM, ROWS, DIM, DIM, bk + l * DIM);
    // V (batched over B, stored transposed: vt[b][d][tok])
    mm_nt<2, false><<<dim3(2, DIM / 128, NBATCH), 256, 0, stream>>>(
        tok_bf, TOKSTRIDE, DIM, wv_t, 0, DIM, vt, VTSTRIDE, KVPAD,
        NTOK, DIM, DIM, bv + l * DIM);

    // scores = Q @ K^T (f32)
    mm_nt<0, false><<<dim3(2, 2, NBATCH), 256, 0, stream>>>(
        qb, TOKSTRIDE, DIM, kb, TOKSTRIDE, DIM, scbuf, SCSTRIDE, NTOK,
        NTOK, NTOK, DIM, nullptr);

    softmax_kernel<<<ROWS, 256, 0, stream>>>(scbuf, Pb, l);

    // attn = P @ V   (NT with B = vt, K = KVPAD=256 zero-padded)
    mm_nt<0, false><<<dim3(2, DIM / 128, NBATCH), 256, 0, stream>>>(
        Pb, PSTRIDE, KVPAD, vt, VTSTRIDE, KVPAD, b4, TOKSTRIDE, DIM,
        NTOK, DIM, KVPAD, nullptr);

    add_ln_kernel<<<ROWS, 256, 0, stream>>>(tok, tok_bf, b4,
        ln1_g + l * DIM, ln1_b + l * DIM);

    // FF1 (+bias+GELU, bf16 out)
    mm_nt<1, true><<<dim3(50, FF_DIM / 128), 256, 0, stream>>>(
        tok_bf, 0, DIM, w1_t, 0, DIM, ffout, 0, FF_DIM,
        ROWS, FF_DIM, DIM, b1 + l * FF_DIM);
    // FF2 (f32 out)
    mm_nt<0, false><<<dim3(50, DIM / 128), 256, 0, stream>>>(
        ffout, 0, FF_DIM, w2_t, 0, FF_DIM, b4, 0, DIM,
        ROWS, DIM, FF_DIM, b2 + l * DIM);

    add_ln_kernel<<<ROWS, 256, 0, stream>>>(tok, tok_bf, b4,
        ln2_g + l * DIM, ln2_b + l * DIM);
  }

  head_kernel<<<NBATCH, 256, 0, stream>>>(tok, lnf_g, lnf_b, head_w, head_b, out);
}